// Round 9
// baseline (352.998 us; speedup 1.0000x reference)
//
#include <hip/hip_runtime.h>
#include <math.h>

typedef _Float16 half_t;
typedef __attribute__((ext_vector_type(8))) _Float16 half8;
typedef __attribute__((ext_vector_type(4))) _Float16 half4;
typedef __attribute__((ext_vector_type(4))) float floatx4;

#define TDIM 36
#define PDIM 161        // 2*80+1 atoms
#define NCOL 50
#define NITER 100
#define PITER2 200      // power steps on G^2 == 400 on G (proven R3-R8)

// loop GEMM: acc = Ghat y : M=176 (11 m-tiles), N=64 (4 n-tiles), K=192 (6 ks)
// epilogue: w = yR + L_inv*Bu - L_inv*acc  (identity channel fp32 regs -> R7 numerics)
#define NKS 6
#define YKS 200         // Yv stride (halves)
#define AKS 192         // Ghat stride (halves), prologue-read only
#define DTS 72          // Dt / Yst stride (halves)
#define SPS 196         // Df fp32 stride
#define GSTR 44
#define BUS 180         // Bu stride (floats): 720B rows, 2-way banks on f4 reads

// ---- LDS map (byte offsets), time-ordered overlays ----
#define BY_YV    0            // [64][YKS] half   25,600   loop buffer 0
#define BY_GHI   25600        // [176][AKS] half  67,584 -> 93,184
#define BY_GLO   93184        //                  67,584 -> 160,768
#define BY_SC    160768       // 1 float: L_inv
#define LDS_TOTAL 160784
#define BY_YV2   93184        // loop buffer 1 (ex-Glo; garbage rows benign: zero-G cols)
#define BY_BU    25600        // [64][BUS] fp32 = 46,080 (ex-Ghi, written post-caching)
#define BY_DF    25600        // [36][SPS] fp32   28,224 (staging + post-loop rebuild)
#define BY_DTH   53824        // [192][DTS] half  27,648 -> 81,472
#define BY_DTL   81472        //                  27,648 -> 109,120
#define BY_YSTH  109120       // [64][DTS] half    9,216 -> 118,336
#define BY_YSTL  118336       //                   9,216 -> 127,552
#define BY_GS    127552       // [36][GSTR] fp32   6,336 -> 133,888
#define BY_G2    133888       //                   6,336 -> 140,224

__device__ __forceinline__ void build_dict(int tid, const float* rho,
                                           const float* theta, float* Df) {
  if (tid < PDIM) {
    if (tid == 0) {
      for (int t = 0; t < TDIM; ++t) Df[t * SPS] = 1.0f;
    } else {
      const bool is_sin = tid > 80;
      const int n = is_sin ? (tid - 81) : (tid - 1);
      const float rr = 0.001f + 1.149f / (1.0f + expf(-rho[n]));
      const float th = 3.14159265358979f / (1.0f + expf(-theta[n]));
      const float lr = logf(rr);
      float s2 = 0.0f;
      for (int t = 0; t < TDIM; ++t) {
        const float ft = (float)t;
        const float val = expf(ft * lr) * (is_sin ? sinf(ft * th) : cosf(ft * th));
        Df[t * SPS + tid] = val;
        s2 += val * val;
      }
      const float inv = 1.0f / sqrtf(s2);
      for (int t = 0; t < TDIM; ++t) Df[t * SPS + tid] *= inv;
    }
  } else if (tid < SPS) {
    for (int t = 0; t < TDIM; ++t) Df[t * SPS + tid] = 0.0f;  // zero column pad
  }
}

// waves_per_eu(2,2): dynamic LDS (160 KB -> 1 block/CU -> 2 waves/SIMD) is invisible
// to the compile-time occupancy heuristic, which otherwise targets 4 waves/SIMD and
// caps VGPRs at 128 -> spills (R7/R8: +5-10 MB WRITE_SIZE). Pinning min=max=2 gives
// the allocator the true 256-reg/wave budget; loop working set ~236 regs fits.
__global__ __launch_bounds__(512) __attribute__((amdgpu_waves_per_eu(2, 2)))
void dan_kernel(const float* __restrict__ xin, const float* __restrict__ rho,
                const float* __restrict__ theta, float* __restrict__ outC,
                float* __restrict__ outDic, float* __restrict__ outR)
{
  extern __shared__ char smc[];
  half_t* Yv0  = (half_t*)(smc + BY_YV);
  half_t* Yv1  = (half_t*)(smc + BY_YV2);
  half_t* Ghi  = (half_t*)(smc + BY_GHI);
  half_t* Glo  = (half_t*)(smc + BY_GLO);
  float*  Bus  = (float*)(smc + BY_BU);
  float*  sc   = (float*)(smc + BY_SC);
  float*  Df   = (float*)(smc + BY_DF);
  half_t* Dth  = (half_t*)(smc + BY_DTH);
  half_t* Dtl  = (half_t*)(smc + BY_DTL);
  half_t* Ysth = (half_t*)(smc + BY_YSTH);
  half_t* Ystl = (half_t*)(smc + BY_YSTL);
  float*  Gs   = (float*)(smc + BY_GS);
  float*  G2   = (float*)(smc + BY_G2);

  const int tid = threadIdx.x;
  const int b = blockIdx.x;
  const int wave = tid >> 6, lane = tid & 63;
  const int q = lane >> 4, ln = lane & 15;
  const int g = wave >> 1, h = wave & 1;     // m-group 0..3, n-half 0..1
  const int nMT = (g == 3) ? 2 : 3;          // m-tiles {g, g+4, g+8}; g=3 -> {3,7}

  // ---- A. zero all LDS
  { unsigned int* z = (unsigned int*)smc;
    for (int i = tid; i < LDS_TOTAL / 4; i += 512) z[i] = 0u; }
  __syncthreads();

  // ---- B. build normalized dictionary (fp32)
  build_dict(tid, rho, theta, Df);
  __syncthreads();

  // ---- C. stage D^T hi/lo, Y^T hi/lo; Gram G = D D^T; dic out
  for (int i = tid; i < TDIM * PDIM; i += 512) {
    const int t = i / PDIM, p = i - t * PDIM;
    const float v = Df[t * SPS + p];
    const half_t hh = (half_t)v;
    Dth[p * DTS + t] = hh;
    Dtl[p * DTS + t] = (half_t)(v - (float)hh);
    if (b == 0) outDic[i] = v;
  }
  { const float* xb = xin + b * TDIM * NCOL;
    for (int i = tid; i < TDIM * NCOL; i += 512) {
      const int t = i / NCOL, c = i - t * NCOL;
      const float v = xb[i];
      const half_t hh = (half_t)v;
      Ysth[c * DTS + t] = hh;
      Ystl[c * DTS + t] = (half_t)(v - (float)hh);
    } }
  for (int job = tid; job < 666; job += 512) {          // 666 = 36*37/2
    int i = 0, rem = job;
    while (rem >= TDIM - i) { rem -= TDIM - i; ++i; }
    const int j = i + rem;
    const float4* ri = (const float4*)(Df + i * SPS);
    const float4* rj = (const float4*)(Df + j * SPS);
    float a = 0.0f;
    #pragma unroll 7
    for (int k = 0; k < SPS / 4; ++k) {
      const float4 x = ri[k], y = rj[k];
      a += x.x * y.x + x.y * y.y + x.z * y.z + x.w * y.w;
    }
    Gs[i * GSTR + j] = a;
    Gs[j * GSTR + i] = a;
  }
  __syncthreads();

  // ---- D. G2 = G*G
  for (int job = tid; job < 666; job += 512) {
    int i = 0, rem = job;
    while (rem >= TDIM - i) { rem -= TDIM - i; ++i; }
    const int j = i + rem;
    const float4* ri = (const float4*)(Gs + i * GSTR);
    const float4* rj = (const float4*)(Gs + j * GSTR);
    float a = 0.0f;
    #pragma unroll
    for (int k = 0; k < GSTR / 4; ++k) {
      const float4 x = ri[k], y = rj[k];
      a += x.x * y.x + x.y * y.y + x.z * y.z + x.w * y.w;
    }
    G2[i * GSTR + j] = a;
    G2[j * GSTR + i] = a;
  }
  __syncthreads();

  // ---- E. wave0: power iteration -> sc[0]=L_inv; all waves: Bu and Gt MFMAs
  if (wave == 0) {
    float g2r[36];
    #pragma unroll
    for (int j = 0; j < 36; ++j) g2r[j] = (lane < 36) ? G2[lane * GSTR + j] : 0.0f;
    float v = (lane < 36) ? 1.0f : 0.0f;
    for (int it = 0; it < PITER2; ++it) {
      const int vi = __float_as_int(v);
      float w0 = 0.0f, w1 = 0.0f;
      #pragma unroll
      for (int j = 0; j < 36; j += 2) {
        w0 = fmaf(g2r[j],     __int_as_float(__builtin_amdgcn_readlane(vi, j)),     w0);
        w1 = fmaf(g2r[j + 1], __int_as_float(__builtin_amdgcn_readlane(vi, j + 1)), w1);
      }
      float w = w0 + w1;
      if ((it & 3) == 3) {
        float s = w * w;
        #pragma unroll
        for (int off = 32; off > 0; off >>= 1) s += __shfl_xor(s, off, 64);
        w *= rsqrtf(s);
      }
      v = w;
    }
    const int vi = __float_as_int(v);
    float w0 = 0.0f, w1 = 0.0f;
    #pragma unroll
    for (int j = 0; j < 36; j += 2) {
      const float gi0 = (lane < 36) ? Gs[lane * GSTR + j]     : 0.0f;
      const float gi1 = (lane < 36) ? Gs[lane * GSTR + j + 1] : 0.0f;
      w0 = fmaf(gi0, __int_as_float(__builtin_amdgcn_readlane(vi, j)),     w0);
      w1 = fmaf(gi1, __int_as_float(__builtin_amdgcn_readlane(vi, j + 1)), w1);
    }
    float num = v * (w0 + w1);
    #pragma unroll
    for (int off = 32; off > 0; off >>= 1) num += __shfl_xor(num, off, 64);
    if (lane == 0) sc[0] = 1.0f / num;
  }

  // A-operand fragments of D^T for this wave's m-tiles (K=t, 2 ks)
  half8 aH[3][2], aL[3][2];
  #pragma unroll
  for (int i = 0; i < 3; ++i) if (i < nMT) {
    const int row = 16 * (g + 4 * i) + ln;
    #pragma unroll
    for (int ks = 0; ks < 2; ++ks) {
      aH[i][ks] = *(const half8*)(Dth + row * DTS + 32 * ks + 8 * q);
      aL[i][ks] = *(const half8*)(Dtl + row * DTS + 32 * ks + 8 * q);
    }
  }
  // Bu = Dt Y (unscaled) at loop C positions
  floatx4 bun[3][2];
  #pragma unroll
  for (int i = 0; i < 3; ++i) { bun[i][0] = (floatx4){0,0,0,0}; bun[i][1] = (floatx4){0,0,0,0}; }
  #pragma unroll
  for (int ks = 0; ks < 2; ++ks) {
    #pragma unroll
    for (int j = 0; j < 2; ++j) {
      const int c = 16 * (2 * h + j) + ln;
      const half8 yh = *(const half8*)(Ysth + c * DTS + 32 * ks + 8 * q);
      const half8 yl = *(const half8*)(Ystl + c * DTS + 32 * ks + 8 * q);
      #pragma unroll
      for (int i = 0; i < 3; ++i) if (i < nMT) {
        bun[i][j] = __builtin_amdgcn_mfma_f32_16x16x32_f16(aH[i][ks], yh, bun[i][j], 0, 0, 0);
        bun[i][j] = __builtin_amdgcn_mfma_f32_16x16x32_f16(aH[i][ks], yl, bun[i][j], 0, 0, 0);
        bun[i][j] = __builtin_amdgcn_mfma_f32_16x16x32_f16(aL[i][ks], yh, bun[i][j], 0, 0, 0);
      }
    }
  }
  // Gt = Dt D ; n-tiles {6h..6h+5}
  floatx4 gt[3][6];
  #pragma unroll
  for (int i = 0; i < 3; ++i)
    #pragma unroll
    for (int nt = 0; nt < 6; ++nt) gt[i][nt] = (floatx4){0,0,0,0};
  #pragma unroll
  for (int nt = 0; nt < 6; ++nt) {
    const int n = 16 * (6 * h + nt) + ln;
    #pragma unroll
    for (int ks = 0; ks < 2; ++ks) {
      const half8 bh = *(const half8*)(Dth + n * DTS + 32 * ks + 8 * q);
      const half8 bl = *(const half8*)(Dtl + n * DTS + 32 * ks + 8 * q);
      #pragma unroll
      for (int i = 0; i < 3; ++i) if (i < nMT) {
        gt[i][nt] = __builtin_amdgcn_mfma_f32_16x16x32_f16(aH[i][ks], bh, gt[i][nt], 0, 0, 0);
        gt[i][nt] = __builtin_amdgcn_mfma_f32_16x16x32_f16(aH[i][ks], bl, gt[i][nt], 0, 0, 0);
        gt[i][nt] = __builtin_amdgcn_mfma_f32_16x16x32_f16(aL[i][ks], bh, gt[i][nt], 0, 0, 0);
      }
    }
  }
  __syncthreads();

  // ---- F. write Ghat = Gt (fp16 hi/lo, NO identity), overwriting phase-1 staging
  #pragma unroll
  for (int i = 0; i < 3; ++i) if (i < nMT) {
    #pragma unroll
    for (int nt = 0; nt < 6; ++nt) {
      const int k = 16 * (6 * h + nt) + ln;
      #pragma unroll
      for (int r = 0; r < 4; ++r) {
        const int m = 16 * (g + 4 * i) + 4 * q + r;
        const float val = gt[i][nt][r];
        const half_t hh = (half_t)val;
        Ghi[m * AKS + k] = hh;
        Glo[m * AKS + k] = (half_t)(val - (float)hh);
      }
    }
  }
  __syncthreads();

  // ---- G. cache loop fragments in registers; read L_inv
  const float L_inv = sc[0];
  const float thr = 0.1f * L_inv;
  half8 GHF[3][NKS], GLF[3][NKS];
  #pragma unroll
  for (int i = 0; i < 3; ++i) if (i < nMT) {
    const int m = 16 * (g + 4 * i) + ln;
    #pragma unroll
    for (int ks = 0; ks < NKS; ++ks) {
      GHF[i][ks] = *(const half8*)(Ghi + m * AKS + 32 * ks + 8 * q);
      GLF[i][ks] = *(const half8*)(Glo + m * AKS + 32 * ks + 8 * q);
    }
  }
  __syncthreads();

  // ---- G2. park pre-scaled Bu in LDS (dead Ghi region); bun regs die here
  #pragma unroll
  for (int i = 0; i < 3; ++i) if (i < nMT) {
    #pragma unroll
    for (int j = 0; j < 2; ++j) {
      const int c = 32 * h + 16 * j + ln;
      const int m0 = 16 * (g + 4 * i) + 4 * q;
      *(float4*)(Bus + c * BUS + m0) = make_float4(L_inv * bun[i][j][0],
                                                   L_inv * bun[i][j][1],
                                                   L_inv * bun[i][j][2],
                                                   L_inv * bun[i][j][3]);
    }
  }
  __syncthreads();

  // ---- H. FISTA loop: one GEMM, double-buffered y, ONE barrier/iter
  float xR[3][2][4], yR[3][2][4];
  #pragma unroll
  for (int i = 0; i < 3; ++i)
    #pragma unroll
    for (int j = 0; j < 2; ++j)
      #pragma unroll
      for (int r = 0; r < 4; ++r) { xR[i][j][r] = 0.0f; yR[i][j][r] = 0.0f; }
  float tk = 1.0f;
  half_t* bufs[2] = {Yv0, Yv1};

  for (int it = 0; it < NITER; ++it) {
    half_t* rd = bufs[it & 1];
    half_t* wr = bufs[(it + 1) & 1];
    floatx4 acc[3][2];
    #pragma unroll
    for (int i = 0; i < 3; ++i) { acc[i][0] = (floatx4){0,0,0,0}; acc[i][1] = (floatx4){0,0,0,0}; }
    #pragma unroll
    for (int ks = 0; ks < NKS; ++ks) {
      const int ko = 32 * ks + 8 * q;
      const half8 b0 = *(const half8*)(rd + (32 * h + ln) * YKS + ko);
      const half8 b1 = *(const half8*)(rd + (32 * h + 16 + ln) * YKS + ko);
      #pragma unroll
      for (int i = 0; i < 3; ++i) if (i < nMT) {
        acc[i][0] = __builtin_amdgcn_mfma_f32_16x16x32_f16(GHF[i][ks], b0, acc[i][0], 0, 0, 0);
        acc[i][0] = __builtin_amdgcn_mfma_f32_16x16x32_f16(GLF[i][ks], b0, acc[i][0], 0, 0, 0);
        acc[i][1] = __builtin_amdgcn_mfma_f32_16x16x32_f16(GHF[i][ks], b1, acc[i][1], 0, 0, 0);
        acc[i][1] = __builtin_amdgcn_mfma_f32_16x16x32_f16(GLF[i][ks], b1, acc[i][1], 0, 0, 0);
      }
    }

    const float tnew = 0.5f * (1.0f + sqrtf(1.0f + 4.0f * tk * tk));
    const float ttf = (tk - 1.0f) / tnew;
    tk = tnew;

    #pragma unroll
    for (int i = 0; i < 3; ++i) if (i < nMT) {
      const int p0 = 16 * (g + 4 * i) + 4 * q;
      #pragma unroll
      for (int j = 0; j < 2; ++j) {
        const int c = 32 * h + 16 * j + ln;
        const float4 cbu = *(const float4*)(Bus + c * BUS + p0);
        const float cb[4] = {cbu.x, cbu.y, cbu.z, cbu.w};
        half4 hv;
        #pragma unroll
        for (int r = 0; r < 4; ++r) {
          // w = yR + L_inv*Bu - L_inv*(Ghat*y)   (identity exact in fp32)
          const float w = fmaf(-L_inv, acc[i][j][r], yR[i][j][r] + cb[r]);
          const float cl = fminf(fmaxf(w, -thr), thr);   // v_med3 clamp
          const float xn = w - cl;                        // softshrink
          const float yn = fmaf(ttf, xn - xR[i][j][r], xn);
          xR[i][j][r] = xn;
          yR[i][j][r] = yn;
          hv[r] = (half_t)yn;
        }
        *(half4*)(wr + c * YKS + p0) = hv;
      }
    }
    __syncthreads();               // writes visible before next iter's reads
  }

  // ---- I. outputs: C = x_fin
  float* Cb = outC + b * PDIM * NCOL;
  #pragma unroll
  for (int i = 0; i < 3; ++i) if (i < nMT) {
    #pragma unroll
    for (int j = 0; j < 2; ++j) {
      const int c = 32 * h + 16 * j + ln;
      #pragma unroll
      for (int r = 0; r < 4; ++r) {
        const int p = 16 * (g + 4 * i) + 4 * q + r;
        if (p < PDIM && c < NCOL) Cb[p * NCOL + c] = xR[i][j][r];
      }
    }
  }
  // stage x (single fp16) into Yv0 for the reconst GEMM (k>=176 pads still zero there)
  #pragma unroll
  for (int i = 0; i < 3; ++i) if (i < nMT) {
    const int p0 = 16 * (g + 4 * i) + 4 * q;
    #pragma unroll
    for (int j = 0; j < 2; ++j) {
      half4 hv;
      #pragma unroll
      for (int r = 0; r < 4; ++r) hv[r] = (half_t)xR[i][j][r];
      *(half4*)(Yv0 + (32 * h + 16 * j + ln) * YKS + p0) = hv;
    }
  }
  __syncthreads();
  // rebuild D fp32 (overwrites dead Bu region)
  build_dict(tid, rho, theta, Df);
  __syncthreads();
  // reconst = D @ C : waves 0..5, M=48(t), N=64(c), K=192(p)
  if (wave < 6) {
    const int mtA = wave >> 1;
    const int ntA = (wave & 1) * 2;
    const int row = 16 * mtA + ln;
    half8 dh[NKS], dl[NKS];
    #pragma unroll
    for (int ks = 0; ks < NKS; ++ks) {
      half8 hh = {0,0,0,0,0,0,0,0}, llv = {0,0,0,0,0,0,0,0};
      if (row < TDIM) {
        const float4 f0 = *(const float4*)(Df + row * SPS + 32 * ks + 8 * q);
        const float4 f1 = *(const float4*)(Df + row * SPS + 32 * ks + 8 * q + 4);
        const float fa[8] = {f0.x, f0.y, f0.z, f0.w, f1.x, f1.y, f1.z, f1.w};
        #pragma unroll
        for (int e = 0; e < 8; ++e) {
          const half_t hcv = (half_t)fa[e];
          hh[e] = hcv;
          llv[e] = (half_t)(fa[e] - (float)hcv);
        }
      }
      dh[ks] = hh; dl[ks] = llv;
    }
    floatx4 a0 = {0,0,0,0}, a1 = {0,0,0,0};
    #pragma unroll
    for (int ks = 0; ks < NKS; ++ks) {
      const int ko = 32 * ks + 8 * q;
      const half8 b0 = *(const half8*)(Yv0 + (16 * ntA + ln) * YKS + ko);
      const half8 b1 = *(const half8*)(Yv0 + (16 * (ntA + 1) + ln) * YKS + ko);
      a0 = __builtin_amdgcn_mfma_f32_16x16x32_f16(dh[ks], b0, a0, 0, 0, 0);
      a0 = __builtin_amdgcn_mfma_f32_16x16x32_f16(dl[ks], b0, a0, 0, 0, 0);
      a1 = __builtin_amdgcn_mfma_f32_16x16x32_f16(dh[ks], b1, a1, 0, 0, 0);
      a1 = __builtin_amdgcn_mfma_f32_16x16x32_f16(dl[ks], b1, a1, 0, 0, 0);
    }
    float* Rb = outR + b * TDIM * NCOL;
    const int t0 = 16 * mtA + 4 * q;
    #pragma unroll
    for (int j = 0; j < 2; ++j) {
      const int c = 16 * (ntA + j) + ln;
      if (c < NCOL) {
        #pragma unroll
        for (int r = 0; r < 4; ++r) {
          const int t = t0 + r;
          if (t < TDIM) Rb[t * NCOL + c] = (j ? a1[r] : a0[r]);
        }
      }
    }
  }
}

// ---------------- launch --------------------------------------------------------------

extern "C" void kernel_launch(void* const* d_in, const int* in_sizes, int n_in,
                              void* d_out, int out_size, void* d_ws, size_t ws_size,
                              hipStream_t stream) {
  const float* x     = (const float*)d_in[0];   // (256, 36, 50)
  const float* rho   = (const float*)d_in[1];   // (80,)
  const float* theta = (const float*)d_in[2];   // (80,)

  float* out    = (float*)d_out;
  float* outC   = out;                              // 256*161*50
  float* outDic = out + 256 * PDIM * NCOL;          // 36*161
  float* outR   = outDic + TDIM * PDIM;             // 256*36*50

  hipLaunchKernelGGL(dan_kernel, dim3(256), dim3(512), LDS_TOTAL, stream,
                     x, rho, theta, outC, outDic, outR);
}

// Round 10
// 305.501 us; speedup vs baseline: 1.1555x; 1.1555x over previous
//
#include <hip/hip_runtime.h>
#include <math.h>

typedef _Float16 half_t;
typedef __attribute__((ext_vector_type(8))) _Float16 half8;
typedef __attribute__((ext_vector_type(4))) _Float16 half4;
typedef __attribute__((ext_vector_type(4))) float floatx4;

#define TDIM 36
#define PDIM 161        // 2*80+1 atoms
#define NCOL 50
#define NITER 100
#define PITER2 200      // power steps on G^2 == 400 on G (proven R3-R9)

// loop GEMM: acc = Ghat y : M=176 (11 m-tiles), N=64 (4 n-tiles), K=160 (5 ks)
//   + fp32 rank-1 fix for Ghat column p=160 in the epilogue
// epilogue: w = yR + L_inv*Bu - L_inv*(acc + g160*y160)   (identity+Bu exact fp32)
#define NKS 5           // loop K-steps (p 0..159)
#define NKA 6           // reconst K-steps (p 0..191)
#define YKS 200         // Yv stride (halves): 100 dw == 4 mod 32, proven bank-balanced
#define GKS 200         // Ghat stride (halves): same pattern as Y reads
#define DTS 72          // Dt / Yst stride (halves)
#define SPS 196         // Df fp32 stride
#define GSTR 44
#define BUS 180         // Bu stride (floats)
#define BUROWS 54       // Bu rows (c<50 valid; clamp reads)

// ---- LDS map (byte offsets), time-ordered overlays ----
#define BY_YV    0            // [64][YKS] half    25,600   loop buffer 0
#define BY_GH    25600        // [176][GKS] half   70,400 -> 96,000  (single-fp16 Ghat)
#define BY_YV2   96000        // [64][YKS] half    25,600 -> 121,600 loop buffer 1
#define BY_BU    121600       // [54][BUS] fp32    38,880 -> 160,480 (written post-E)
#define BY_SC    160480       // 1 float: L_inv
#define LDS_TOTAL 160484
// prologue-only aliases (all consumed before their regions are overwritten):
#define BY_DF    25600        // [36][SPS] fp32   28,224 -> 53,824
#define BY_DTH   53824        // [192][DTS] half  27,648 -> 81,472
#define BY_DTL   81472        //                  27,648 -> 109,120
#define BY_YSTH  109120       // [64][DTS] half    9,216 -> 118,336
#define BY_YSTL  118336       //                   9,216 -> 127,552
#define BY_GS    127552       // [36][GSTR] fp32   6,336 -> 133,888
#define BY_G2    133888       //                   6,336 -> 140,224

__device__ __forceinline__ void build_dict(int tid, const float* rho,
                                           const float* theta, float* Df) {
  if (tid < PDIM) {
    if (tid == 0) {
      for (int t = 0; t < TDIM; ++t) Df[t * SPS] = 1.0f;
    } else {
      const bool is_sin = tid > 80;
      const int n = is_sin ? (tid - 81) : (tid - 1);
      const float rr = 0.001f + 1.149f / (1.0f + expf(-rho[n]));
      const float th = 3.14159265358979f / (1.0f + expf(-theta[n]));
      const float lr = logf(rr);
      float s2 = 0.0f;
      for (int t = 0; t < TDIM; ++t) {
        const float ft = (float)t;
        const float val = expf(ft * lr) * (is_sin ? sinf(ft * th) : cosf(ft * th));
        Df[t * SPS + tid] = val;
        s2 += val * val;
      }
      const float inv = 1.0f / sqrtf(s2);
      for (int t = 0; t < TDIM; ++t) Df[t * SPS + tid] *= inv;
    }
  } else if (tid < SPS) {
    for (int t = 0; t < TDIM; ++t) Df[t * SPS + tid] = 0.0f;  // zero column pad
  }
}

__global__ __launch_bounds__(512)
void dan_kernel(const float* __restrict__ xin, const float* __restrict__ rho,
                const float* __restrict__ theta, float* __restrict__ outC,
                float* __restrict__ outDic, float* __restrict__ outR)
{
  extern __shared__ char smc[];
  half_t* Yv0  = (half_t*)(smc + BY_YV);
  half_t* Yv1  = (half_t*)(smc + BY_YV2);
  half_t* Gh   = (half_t*)(smc + BY_GH);
  float*  Bus  = (float*)(smc + BY_BU);
  float*  sc   = (float*)(smc + BY_SC);
  float*  Df   = (float*)(smc + BY_DF);
  half_t* Dth  = (half_t*)(smc + BY_DTH);
  half_t* Dtl  = (half_t*)(smc + BY_DTL);
  half_t* Ysth = (half_t*)(smc + BY_YSTH);
  half_t* Ystl = (half_t*)(smc + BY_YSTL);
  float*  Gs   = (float*)(smc + BY_GS);
  float*  G2   = (float*)(smc + BY_G2);

  const int tid = threadIdx.x;
  const int b = blockIdx.x;
  const int wave = tid >> 6, lane = tid & 63;
  const int q = lane >> 4, ln = lane & 15;
  const int g = wave >> 1, h = wave & 1;     // m-group 0..3, n-half 0..1
  const int nMT = (g == 3) ? 2 : 3;          // m-tiles {g, g+4, g+8}; g=3 -> {3,7}

  // ---- A. zero all LDS
  { unsigned int* z = (unsigned int*)smc;
    for (int i = tid; i < LDS_TOTAL / 4; i += 512) z[i] = 0u; }
  __syncthreads();

  // ---- B. build normalized dictionary (fp32)
  build_dict(tid, rho, theta, Df);
  __syncthreads();

  // ---- C. stage D^T hi/lo, Y^T hi/lo; Gram G = D D^T; dic out
  for (int i = tid; i < TDIM * PDIM; i += 512) {
    const int t = i / PDIM, p = i - t * PDIM;
    const float v = Df[t * SPS + p];
    const half_t hh = (half_t)v;
    Dth[p * DTS + t] = hh;
    Dtl[p * DTS + t] = (half_t)(v - (float)hh);
    if (b == 0) outDic[i] = v;
  }
  { const float* xb = xin + b * TDIM * NCOL;
    for (int i = tid; i < TDIM * NCOL; i += 512) {
      const int t = i / NCOL, c = i - t * NCOL;
      const float v = xb[i];
      const half_t hh = (half_t)v;
      Ysth[c * DTS + t] = hh;
      Ystl[c * DTS + t] = (half_t)(v - (float)hh);
    } }
  for (int job = tid; job < 666; job += 512) {          // 666 = 36*37/2
    int i = 0, rem = job;
    while (rem >= TDIM - i) { rem -= TDIM - i; ++i; }
    const int j = i + rem;
    const float4* ri = (const float4*)(Df + i * SPS);
    const float4* rj = (const float4*)(Df + j * SPS);
    float a = 0.0f;
    #pragma unroll 7
    for (int k = 0; k < SPS / 4; ++k) {
      const float4 x = ri[k], y = rj[k];
      a += x.x * y.x + x.y * y.y + x.z * y.z + x.w * y.w;
    }
    Gs[i * GSTR + j] = a;
    Gs[j * GSTR + i] = a;
  }
  __syncthreads();

  // ---- D. G2 = G*G
  for (int job = tid; job < 666; job += 512) {
    int i = 0, rem = job;
    while (rem >= TDIM - i) { rem -= TDIM - i; ++i; }
    const int j = i + rem;
    const float4* ri = (const float4*)(Gs + i * GSTR);
    const float4* rj = (const float4*)(Gs + j * GSTR);
    float a = 0.0f;
    #pragma unroll
    for (int k = 0; k < GSTR / 4; ++k) {
      const float4 x = ri[k], y = rj[k];
      a += x.x * y.x + x.y * y.y + x.z * y.z + x.w * y.w;
    }
    G2[i * GSTR + j] = a;
    G2[j * GSTR + i] = a;
  }
  __syncthreads();

  // ---- E. wave0: power iteration -> sc[0]=L_inv; all waves: Bu and Gt MFMAs
  if (wave == 0) {
    float g2r[36];
    #pragma unroll
    for (int j = 0; j < 36; ++j) g2r[j] = (lane < 36) ? G2[lane * GSTR + j] : 0.0f;
    float v = (lane < 36) ? 1.0f : 0.0f;
    for (int it = 0; it < PITER2; ++it) {
      const int vi = __float_as_int(v);
      float w0 = 0.0f, w1 = 0.0f;
      #pragma unroll
      for (int j = 0; j < 36; j += 2) {
        w0 = fmaf(g2r[j],     __int_as_float(__builtin_amdgcn_readlane(vi, j)),     w0);
        w1 = fmaf(g2r[j + 1], __int_as_float(__builtin_amdgcn_readlane(vi, j + 1)), w1);
      }
      float w = w0 + w1;
      if ((it & 3) == 3) {
        float s = w * w;
        #pragma unroll
        for (int off = 32; off > 0; off >>= 1) s += __shfl_xor(s, off, 64);
        w *= rsqrtf(s);
      }
      v = w;
    }
    const int vi = __float_as_int(v);
    float w0 = 0.0f, w1 = 0.0f;
    #pragma unroll
    for (int j = 0; j < 36; j += 2) {
      const float gi0 = (lane < 36) ? Gs[lane * GSTR + j]     : 0.0f;
      const float gi1 = (lane < 36) ? Gs[lane * GSTR + j + 1] : 0.0f;
      w0 = fmaf(gi0, __int_as_float(__builtin_amdgcn_readlane(vi, j)),     w0);
      w1 = fmaf(gi1, __int_as_float(__builtin_amdgcn_readlane(vi, j + 1)), w1);
    }
    float num = v * (w0 + w1);
    #pragma unroll
    for (int off = 32; off > 0; off >>= 1) num += __shfl_xor(num, off, 64);
    if (lane == 0) sc[0] = 1.0f / num;
  }

  // A-operand fragments of D^T for this wave's m-tiles (K=t, 2 ks)
  half8 aH[3][2], aL[3][2];
  #pragma unroll
  for (int i = 0; i < 3; ++i) if (i < nMT) {
    const int row = 16 * (g + 4 * i) + ln;
    #pragma unroll
    for (int ks = 0; ks < 2; ++ks) {
      aH[i][ks] = *(const half8*)(Dth + row * DTS + 32 * ks + 8 * q);
      aL[i][ks] = *(const half8*)(Dtl + row * DTS + 32 * ks + 8 * q);
    }
  }
  // Bu = Dt Y (unscaled) at loop C positions  (near-fp32 via 3-term hi/lo)
  floatx4 bun[3][2];
  #pragma unroll
  for (int i = 0; i < 3; ++i) { bun[i][0] = (floatx4){0,0,0,0}; bun[i][1] = (floatx4){0,0,0,0}; }
  #pragma unroll
  for (int ks = 0; ks < 2; ++ks) {
    #pragma unroll
    for (int j = 0; j < 2; ++j) {
      const int c = 16 * (2 * h + j) + ln;
      const half8 yh = *(const half8*)(Ysth + c * DTS + 32 * ks + 8 * q);
      const half8 yl = *(const half8*)(Ystl + c * DTS + 32 * ks + 8 * q);
      #pragma unroll
      for (int i = 0; i < 3; ++i) if (i < nMT) {
        bun[i][j] = __builtin_amdgcn_mfma_f32_16x16x32_f16(aH[i][ks], yh, bun[i][j], 0, 0, 0);
        bun[i][j] = __builtin_amdgcn_mfma_f32_16x16x32_f16(aH[i][ks], yl, bun[i][j], 0, 0, 0);
        bun[i][j] = __builtin_amdgcn_mfma_f32_16x16x32_f16(aL[i][ks], yh, bun[i][j], 0, 0, 0);
      }
    }
  }
  // Gt = Dt D (near-fp32); n-tiles {6h..6h+5}
  floatx4 gt[3][6];
  #pragma unroll
  for (int i = 0; i < 3; ++i)
    #pragma unroll
    for (int nt = 0; nt < 6; ++nt) gt[i][nt] = (floatx4){0,0,0,0};
  #pragma unroll
  for (int nt = 0; nt < 6; ++nt) {
    const int n = 16 * (6 * h + nt) + ln;
    #pragma unroll
    for (int ks = 0; ks < 2; ++ks) {
      const half8 bh = *(const half8*)(Dth + n * DTS + 32 * ks + 8 * q);
      const half8 bl = *(const half8*)(Dtl + n * DTS + 32 * ks + 8 * q);
      #pragma unroll
      for (int i = 0; i < 3; ++i) if (i < nMT) {
        gt[i][nt] = __builtin_amdgcn_mfma_f32_16x16x32_f16(aH[i][ks], bh, gt[i][nt], 0, 0, 0);
        gt[i][nt] = __builtin_amdgcn_mfma_f32_16x16x32_f16(aH[i][ks], bl, gt[i][nt], 0, 0, 0);
        gt[i][nt] = __builtin_amdgcn_mfma_f32_16x16x32_f16(aL[i][ks], bh, gt[i][nt], 0, 0, 0);
      }
    }
  }
  __syncthreads();

  // ---- F. write Ghat single fp16 (rounded once from near-fp32 Gt)
  #pragma unroll
  for (int i = 0; i < 3; ++i) if (i < nMT) {
    #pragma unroll
    for (int nt = 0; nt < 6; ++nt) {
      const int k = 16 * (6 * h + nt) + ln;
      #pragma unroll
      for (int r = 0; r < 4; ++r) {
        const int m = 16 * (g + 4 * i) + 4 * q + r;
        Gh[m * GKS + k] = (half_t)gt[i][nt][r];
      }
    }
  }
  __syncthreads();

  // ---- G. park pre-scaled Bu in LDS; hoist fp32 Ghat col-160 into registers
  const float L_inv = sc[0];
  const float thr = 0.1f * L_inv;
  #pragma unroll
  for (int i = 0; i < 3; ++i) if (i < nMT) {
    #pragma unroll
    for (int j = 0; j < 2; ++j) {
      const int c = 32 * h + 16 * j + ln;
      if (c < BUROWS) {
        const int m0 = 16 * (g + 4 * i) + 4 * q;
        *(float4*)(Bus + c * BUS + m0) = make_float4(L_inv * bun[i][j][0],
                                                     L_inv * bun[i][j][1],
                                                     L_inv * bun[i][j][2],
                                                     L_inv * bun[i][j][3]);
      }
    }
  }
  float g160[3][4];
  #pragma unroll
  for (int i = 0; i < 3; ++i) if (i < nMT) {
    #pragma unroll
    for (int r = 0; r < 4; ++r)
      g160[i][r] = (float)Gh[(16 * (g + 4 * i) + 4 * q + r) * GKS + 160];
  }
  __syncthreads();

  // ---- H. FISTA loop: one GEMM (G from LDS), double-buffered y, ONE barrier/iter
  float xR[3][2][4], yR[3][2][4];
  #pragma unroll
  for (int i = 0; i < 3; ++i)
    #pragma unroll
    for (int j = 0; j < 2; ++j)
      #pragma unroll
      for (int r = 0; r < 4; ++r) { xR[i][j][r] = 0.0f; yR[i][j][r] = 0.0f; }
  float tk = 1.0f;
  half_t* bufs[2] = {Yv0, Yv1};

  for (int it = 0; it < NITER; ++it) {
    half_t* rd = bufs[it & 1];
    half_t* wr = bufs[(it + 1) & 1];
    floatx4 acc[3][2];
    #pragma unroll
    for (int i = 0; i < 3; ++i) { acc[i][0] = (floatx4){0,0,0,0}; acc[i][1] = (floatx4){0,0,0,0}; }
    #pragma unroll
    for (int ks = 0; ks < NKS; ++ks) {
      const int ko = 32 * ks + 8 * q;
      const half8 b0 = *(const half8*)(rd + (32 * h + ln) * YKS + ko);
      const half8 b1 = *(const half8*)(rd + (32 * h + 16 + ln) * YKS + ko);
      #pragma unroll
      for (int i = 0; i < 3; ++i) if (i < nMT) {
        const half8 gf = *(const half8*)(Gh + (16 * (g + 4 * i) + ln) * GKS + ko);
        acc[i][0] = __builtin_amdgcn_mfma_f32_16x16x32_f16(gf, b0, acc[i][0], 0, 0, 0);
        acc[i][1] = __builtin_amdgcn_mfma_f32_16x16x32_f16(gf, b1, acc[i][1], 0, 0, 0);
      }
    }
    // p=160 column of y (fp32 rank-1 fix in epilogue)
    const float y160a = (float)rd[(32 * h + ln) * YKS + 160];
    const float y160b = (float)rd[(32 * h + 16 + ln) * YKS + 160];

    const float tnew = 0.5f * (1.0f + sqrtf(1.0f + 4.0f * tk * tk));
    const float ttf = (tk - 1.0f) / tnew;
    tk = tnew;

    #pragma unroll
    for (int i = 0; i < 3; ++i) if (i < nMT) {
      const int p0 = 16 * (g + 4 * i) + 4 * q;
      #pragma unroll
      for (int j = 0; j < 2; ++j) {
        const int c = 32 * h + 16 * j + ln;
        const int cc = (c < BUROWS) ? c : (BUROWS - 1);
        const float4 cbu = *(const float4*)(Bus + cc * BUS + p0);
        const float cb[4] = {cbu.x, cbu.y, cbu.z, cbu.w};
        const float y16 = j ? y160b : y160a;
        half4 hv;
        #pragma unroll
        for (int r = 0; r < 4; ++r) {
          const float gy = fmaf(g160[i][r], y16, acc[i][j][r]);
          // w = yR + L_inv*Bu - L_inv*(Ghat*y)_full   (identity exact in fp32)
          const float w = fmaf(-L_inv, gy, yR[i][j][r] + cb[r]);
          const float cl = fminf(fmaxf(w, -thr), thr);   // v_med3 clamp
          const float xn = w - cl;                        // softshrink
          const float yn = fmaf(ttf, xn - xR[i][j][r], xn);
          xR[i][j][r] = xn;
          yR[i][j][r] = yn;
          hv[r] = (half_t)yn;
        }
        *(half4*)(wr + c * YKS + p0) = hv;
      }
    }
    __syncthreads();               // writes visible before next iter's reads
  }

  // ---- I. outputs: C = x_fin
  float* Cb = outC + b * PDIM * NCOL;
  #pragma unroll
  for (int i = 0; i < 3; ++i) if (i < nMT) {
    #pragma unroll
    for (int j = 0; j < 2; ++j) {
      const int c = 32 * h + 16 * j + ln;
      #pragma unroll
      for (int r = 0; r < 4; ++r) {
        const int p = 16 * (g + 4 * i) + 4 * q + r;
        if (p < PDIM && c < NCOL) Cb[p * NCOL + c] = xR[i][j][r];
      }
    }
  }
  // stage x (single fp16) into Yv0 for the reconst GEMM (cols p>=176 still zero there)
  #pragma unroll
  for (int i = 0; i < 3; ++i) if (i < nMT) {
    const int p0 = 16 * (g + 4 * i) + 4 * q;
    #pragma unroll
    for (int j = 0; j < 2; ++j) {
      half4 hv;
      #pragma unroll
      for (int r = 0; r < 4; ++r) hv[r] = (half_t)xR[i][j][r];
      *(half4*)(Yv0 + (32 * h + 16 * j + ln) * YKS + p0) = hv;
    }
  }
  __syncthreads();
  // rebuild D fp32 (overwrites dead Ghat region)
  build_dict(tid, rho, theta, Df);
  __syncthreads();
  // reconst = D @ C : waves 0..5, M=48(t), N=64(c), K=192(p)
  if (wave < 6) {
    const int mtA = wave >> 1;
    const int ntA = (wave & 1) * 2;
    const int row = 16 * mtA + ln;
    half8 dh[NKA], dl[NKA];
    #pragma unroll
    for (int ks = 0; ks < NKA; ++ks) {
      half8 hh = {0,0,0,0,0,0,0,0}, llv = {0,0,0,0,0,0,0,0};
      if (row < TDIM) {
        const float4 f0 = *(const float4*)(Df + row * SPS + 32 * ks + 8 * q);
        const float4 f1 = *(const float4*)(Df + row * SPS + 32 * ks + 8 * q + 4);
        const float fa[8] = {f0.x, f0.y, f0.z, f0.w, f1.x, f1.y, f1.z, f1.w};
        #pragma unroll
        for (int e = 0; e < 8; ++e) {
          const half_t hcv = (half_t)fa[e];
          hh[e] = hcv;
          llv[e] = (half_t)(fa[e] - (float)hcv);
        }
      }
      dh[ks] = hh; dl[ks] = llv;
    }
    floatx4 a0 = {0,0,0,0}, a1 = {0,0,0,0};
    #pragma unroll
    for (int ks = 0; ks < NKA; ++ks) {
      const int ko = 32 * ks + 8 * q;
      const half8 b0 = *(const half8*)(Yv0 + (16 * ntA + ln) * YKS + ko);
      const half8 b1 = *(const half8*)(Yv0 + (16 * (ntA + 1) + ln) * YKS + ko);
      a0 = __builtin_amdgcn_mfma_f32_16x16x32_f16(dh[ks], b0, a0, 0, 0, 0);
      a0 = __builtin_amdgcn_mfma_f32_16x16x32_f16(dl[ks], b0, a0, 0, 0, 0);
      a1 = __builtin_amdgcn_mfma_f32_16x16x32_f16(dh[ks], b1, a1, 0, 0, 0);
      a1 = __builtin_amdgcn_mfma_f32_16x16x32_f16(dl[ks], b1, a1, 0, 0, 0);
    }
    float* Rb = outR + b * TDIM * NCOL;
    const int t0 = 16 * mtA + 4 * q;
    #pragma unroll
    for (int j = 0; j < 2; ++j) {
      const int c = 16 * (ntA + j) + ln;
      if (c < NCOL) {
        #pragma unroll
        for (int r = 0; r < 4; ++r) {
          const int t = t0 + r;
          if (t < TDIM) Rb[t * NCOL + c] = (j ? a1[r] : a0[r]);
        }
      }
    }
  }
}

// ---------------- launch --------------------------------------------------------------

extern "C" void kernel_launch(void* const* d_in, const int* in_sizes, int n_in,
                              void* d_out, int out_size, void* d_ws, size_t ws_size,
                              hipStream_t stream) {
  const float* x     = (const float*)d_in[0];   // (256, 36, 50)
  const float* rho   = (const float*)d_in[1];   // (80,)
  const float* theta = (const float*)d_in[2];   // (80,)

  float* out    = (float*)d_out;
  float* outC   = out;                              // 256*161*50
  float* outDic = out + 256 * PDIM * NCOL;          // 36*161
  float* outR   = outDic + TDIM * PDIM;             // 256*36*50

  hipLaunchKernelGGL(dan_kernel, dim3(256), dim3(512), LDS_TOTAL, stream,
                     x, rho, theta, outC, outDic, outR);
}